// Round 12
// baseline (336.833 us; speedup 1.0000x reference)
//
#include <hip/hip_runtime.h>
#include <cstddef>
#include <cstdint>

// B=2, NF=8(seq), DIM=128, HW=1600 -> Bp=3200 positions, M=25600 token rows
// HID=256, INNER=512, NH=128, DH=4

#define NPOS 3200
#define MTOK 25600

typedef __attribute__((ext_vector_type(8))) short short8;
typedef __attribute__((ext_vector_type(8))) unsigned short u16x8;
typedef __attribute__((ext_vector_type(4))) float f32x4;

__device__ __forceinline__ float bf2f(unsigned short u) {
  union { uint32_t i; float f; } v; v.i = ((uint32_t)u) << 16; return v.f;
}
__device__ __forceinline__ unsigned short f2bf(float f) {
  union { float f; uint32_t i; } v; v.f = f;
  uint32_t r = (v.i + 0x7fffu + ((v.i >> 16) & 1u)) >> 16;
  return (unsigned short)r;
}
__device__ __forceinline__ float geluf(float x) {
  return 0.5f * x * (1.0f + erff(x * 0.70710678118654752f));
}
__device__ __forceinline__ float fast_rcp(float x) { return __builtin_amdgcn_rcpf(x); }
__device__ __forceinline__ float silu_fast(float x) {
  return x * fast_rcp(1.0f + __expf(-x));
}

// bf16 weight-buffer offsets (elements)
#define OFF_FC1 0
#define OFF_FC2 16384
#define OFF_OFC1 49152
#define OFF_OFC2 114688
#define OFF_UP 147456
#define OFF_DW 671744
#define OFF_GW 933888
#define WB_ELEMS 1458176

// ---------- merged weight prep (gate rows interleaved: col 2n=ig_n, 2n+1=fg_n) ----------
__global__ __launch_bounds__(256) void wprep(const float* __restrict__ fc1w,
                                             const float* __restrict__ fc2w,
                                             const float* __restrict__ ofc1w,
                                             const float* __restrict__ ofc2w,
                                             const float* __restrict__ upw,
                                             const float* __restrict__ dww,
                                             const float* __restrict__ igw,
                                             const float* __restrict__ fgw,
                                             const float* __restrict__ qw,
                                             const float* __restrict__ kw,
                                             const float* __restrict__ igbias,
                                             const float* __restrict__ fgbias,
                                             unsigned short* __restrict__ wb,
                                             float* __restrict__ gbias) {
  int i = blockIdx.x * 256 + threadIdx.x;
  if (i < 16384) { wb[OFF_FC1 + i] = f2bf(fc1w[i]); return; }
  i -= 16384;
  if (i < 32768) { wb[OFF_FC2 + i] = f2bf(fc2w[i]); return; }
  i -= 32768;
  if (i < 65536) { wb[OFF_OFC1 + i] = f2bf(ofc1w[i]); return; }
  i -= 65536;
  if (i < 32768) { wb[OFF_OFC2 + i] = f2bf(ofc2w[i]); return; }
  i -= 32768;
  if (i < 524288) { wb[OFF_UP + i] = f2bf(upw[i]); return; }
  i -= 524288;
  if (i < 262144) { wb[OFF_DW + i] = f2bf(dww[i]); return; }
  i -= 262144;
  if (i < 262144) {  // gx part of gate weight: W[2*row+gate, 512 + c]
    const int l = i >> 17;
    const int r = i & 131071;
    const int gate = r >> 16;
    const int rr = r & 65535;
    const int row = rr >> 9, c = rr & 511;
    const float* src = (gate ? fgw : igw) + (size_t)l * 196608 + (size_t)row * 1536 + 1024 + c;
    wb[OFF_GW + (size_t)l * 262144 + (size_t)(2 * row + gate) * 1024 + 512 + c] = f2bf(*src);
    return;
  }
  i -= 262144;
  if (i < 131072) {  // fold part: W[2*jj+gate, c], c<512
    const int l = i >> 16;
    const int r = i & 65535;
    const int jj = r >> 9, c = r & 511;
    const int n = c >> 2, d = c & 3;
    const float* igp = igw + (size_t)l * 196608;
    const float* fgp = fgw + (size_t)l * 196608;
    const float* qp = qw + l * 2048;
    const float* kp = kw + l * 2048;
    float si = 0.f, sf = 0.f;
#pragma unroll
    for (int e = 0; e < 4; ++e) {
      const float qv = qp[n * 16 + e * 4 + d];
      const float kv = kp[n * 16 + e * 4 + d];
      si += igp[jj * 1536 + n * 4 + e] * qv + igp[jj * 1536 + 512 + n * 4 + e] * kv;
      sf += fgp[jj * 1536 + n * 4 + e] * qv + fgp[jj * 1536 + 512 + n * 4 + e] * kv;
    }
    wb[OFF_GW + (size_t)l * 262144 + (size_t)(2 * jj) * 1024 + c] = f2bf(si);
    wb[OFF_GW + (size_t)l * 262144 + (size_t)(2 * jj + 1) * 1024 + c] = f2bf(sf);
    return;
  }
  i -= 131072;
  if (i < 512) {
    const int l = i >> 8, c = i & 255;
    gbias[l * 256 + c] = (c & 1) ? fgbias[l * 128 + (c >> 1)] : igbias[l * 128 + (c >> 1)];
  }
}

// ---------- transpose in: x (B,1024,1600) fp32 -> xflat (B*1600, 1024) bf16 ----------
__global__ __launch_bounds__(256) void trans_in(const float* __restrict__ x,
                                                unsigned short* __restrict__ xf) {
  __shared__ float tile[32][33];
  const int b = blockIdx.z;
  const int hw0 = blockIdx.x * 32;
  const int sc0 = blockIdx.y * 32;
  const int tx = threadIdx.x, ty = threadIdx.y;  // 32 x 8
#pragma unroll
  for (int i = 0; i < 32; i += 8)
    tile[ty + i][tx] = x[((size_t)b * 1024 + sc0 + ty + i) * 1600 + hw0 + tx];
  __syncthreads();
#pragma unroll
  for (int i = 0; i < 32; i += 8)
    xf[((size_t)b * 1600 + hw0 + ty + i) * 1024 + sc0 + tx] = f2bf(tile[tx][ty + i]);
}

// ---------- transpose out ----------
__global__ __launch_bounds__(256) void trans_out(const float* __restrict__ x,
                                                 const unsigned short* __restrict__ o,
                                                 float* __restrict__ out) {
  __shared__ float tile[32][33];
  const int b = blockIdx.z;
  const int hw0 = blockIdx.x * 32;
  const int sc0 = blockIdx.y * 32;
  const int tx = threadIdx.x, ty = threadIdx.y;
#pragma unroll
  for (int i = 0; i < 32; i += 8)
    tile[ty + i][tx] = bf2f(o[((size_t)b * 1600 + hw0 + ty + i) * 1024 + sc0 + tx]);
  __syncthreads();
#pragma unroll
  for (int i = 0; i < 32; i += 8) {
    size_t idx = ((size_t)b * 1024 + sc0 + ty + i) * 1600 + hw0 + tx;
    out[idx] = x[idx] + tile[tx][ty + i];
  }
}

// ---------- MFMA bf16 GEMM: reg-staged, double-buffered LDS, 1 barrier/step, XCD swizzle ----
// A split over K: cols [0,KA) from A (lda), [KA,K) from A2 (lda2). W: bf16 (N x ldw).
// 128x128 tile, BK=32, 4 waves, 64x64/wave. LDS [buf][kc][row][8].
// LNF=1: A rows are flip-mapped hbuf rows; per-row LayerNorm (stats pre-loop) is applied
//        during staging (inside swrite, so loads stay early / use stays late).
// MODE 0: C_bf16 = v + bias
// MODE 1: C_bf16 = gelu(v + bias)
// MODE 2: C_bf16[flip-row] += v + bias         (RMW bf16)
// MODE 6: C_bf16[flip-row] = Cin_bf16[flip-row] + v + bias
template <int MODE, int LNF>
__global__ __launch_bounds__(256) void mgemm(const unsigned short* __restrict__ A, int lda,
                                             const unsigned short* __restrict__ A2, int lda2,
                                             int KA,
                                             const unsigned short* __restrict__ W, int ldw,
                                             const float* __restrict__ bias,
                                             const unsigned short* __restrict__ Cin,
                                             void* __restrict__ Cv, int ldc, int K,
                                             int flip,
                                             const float* __restrict__ lnw,
                                             const float* __restrict__ lnb) {
  __shared__ __align__(16) unsigned short Als[2][4][128][8];  // 16 KB
  __shared__ __align__(16) unsigned short Bls[2][4][128][8];  // 16 KB
  const int t = threadIdx.x;
  const int lane = t & 63, wid = t >> 6;
  const int wr = wid >> 1, wc = wid & 1;
  // XCD-aware bijective chunked swizzle (all grids here have nwg % 8 == 0, gridDim.x pow2)
  const int nwg = gridDim.x * gridDim.y;
  const int bid = blockIdx.y * gridDim.x + blockIdx.x;
  const int q = nwg >> 3, r = nwg & 7;
  const int xcd = bid & 7, idx = bid >> 3;
  const int swz = (xcd < r ? xcd * (q + 1) : r * (q + 1) + (xcd - r) * q) + idx;
  const int bx = swz & (gridDim.x - 1);
  const int by = swz >> (31 - __builtin_clz(gridDim.x));
  const int bm = by * 128, bn = bx * 128;
  const int srow = t >> 1;       // 0..127
  const int skh = (t & 1) << 4;  // 0 or 16
  const int ch = skh >> 3;       // 0 or 2
  const int kc = lane >> 4;
  const int lr = lane & 15;
  f32x4 acc[4][4] = {};
  const unsigned short* Wp = W + (size_t)(bn + srow) * ldw + skh;

  // LNF: flip-mapped source row + per-row LN stats
  const int sr2 = (LNF && flip) ? ((srow & ~7) | (7 - (srow & 7))) : srow;
  float mu_r = 0.f, rinv_r = 0.f;
  if (LNF) {
    const int hh = t & 1;
    const unsigned short* hrow = A + (size_t)(bm + sr2) * lda + hh * 128;
    float s = 0.f, sq = 0.f;
#pragma unroll
    for (int c = 0; c < 16; ++c) {
      u16x8 v = *(const u16x8*)(hrow + c * 8);
#pragma unroll
      for (int e = 0; e < 8; ++e) { const float f = bf2f(v[e]); s += f; sq += f * f; }
    }
    s += __shfl_xor(s, 1);
    sq += __shfl_xor(sq, 1);
    const float mu = s * (1.f / 256.f);
    const float var = sq * (1.f / 256.f) - mu * mu;
    mu_r = mu;
    rinv_r = rsqrtf(var + 1e-5f);
  }

  auto gload = [&](int k0, u16x8& a0, u16x8& a1, u16x8& b0, u16x8& b1) {
    const unsigned short* Ab;
    int kk, ldA;
    if (k0 < KA) { Ab = A; kk = k0; ldA = lda; }
    else { Ab = A2; kk = k0 - KA; ldA = lda2; }
    const unsigned short* ap = Ab + (size_t)(bm + (LNF ? sr2 : srow)) * ldA + kk + skh;
    a0 = *(const u16x8*)ap;
    a1 = *(const u16x8*)(ap + 8);
    b0 = *(const u16x8*)(Wp + k0);
    b1 = *(const u16x8*)(Wp + k0 + 8);
  };
  auto lnmap = [&](u16x8 raw, int col0) -> u16x8 {
    u16x8 o;
    const float4 g0 = *(const float4*)(lnw + col0);
    const float4 g1 = *(const float4*)(lnw + col0 + 4);
    const float4 bb0 = *(const float4*)(lnb + col0);
    const float4 bb1 = *(const float4*)(lnb + col0 + 4);
    o[0] = f2bf((bf2f(raw[0]) - mu_r) * rinv_r * g0.x + bb0.x);
    o[1] = f2bf((bf2f(raw[1]) - mu_r) * rinv_r * g0.y + bb0.y);
    o[2] = f2bf((bf2f(raw[2]) - mu_r) * rinv_r * g0.z + bb0.z);
    o[3] = f2bf((bf2f(raw[3]) - mu_r) * rinv_r * g0.w + bb0.w);
    o[4] = f2bf((bf2f(raw[4]) - mu_r) * rinv_r * g1.x + bb1.x);
    o[5] = f2bf((bf2f(raw[5]) - mu_r) * rinv_r * g1.y + bb1.y);
    o[6] = f2bf((bf2f(raw[6]) - mu_r) * rinv_r * g1.z + bb1.z);
    o[7] = f2bf((bf2f(raw[7]) - mu_r) * rinv_r * g1.w + bb1.w);
    return o;
  };
  auto swrite = [&](int buf, int kw0, u16x8 a0, u16x8 a1, u16x8 b0, u16x8 b1) {
    if (LNF) {
      a0 = lnmap(a0, kw0 + skh);
      a1 = lnmap(a1, kw0 + skh + 8);
    }
    *(u16x8*)&Als[buf][ch][srow][0] = a0;
    *(u16x8*)&Als[buf][ch + 1][srow][0] = a1;
    *(u16x8*)&Bls[buf][ch][srow][0] = b0;
    *(u16x8*)&Bls[buf][ch + 1][srow][0] = b1;
  };

  u16x8 ca0, ca1, cb0, cb1;
  gload(0, ca0, ca1, cb0, cb1);
  swrite(0, 0, ca0, ca1, cb0, cb1);
  if (K > 32) gload(32, ca0, ca1, cb0, cb1);
  __syncthreads();
  int cur = 0;
  for (int k0 = 0; k0 < K; k0 += 32) {
    u16x8 na0, na1, nb0, nb1;
    if (k0 + 64 < K) gload(k0 + 64, na0, na1, nb0, nb1);  // issue early, consumed next step
    short8 af[4], bf[4];
#pragma unroll
    for (int mi = 0; mi < 4; ++mi)
      af[mi] = *(const short8*)&Als[cur][kc][wr * 64 + mi * 16 + lr][0];
#pragma unroll
    for (int ni = 0; ni < 4; ++ni)
      bf[ni] = *(const short8*)&Bls[cur][kc][wc * 64 + ni * 16 + lr][0];
#pragma unroll
    for (int mi = 0; mi < 4; ++mi)
#pragma unroll
      for (int ni = 0; ni < 4; ++ni)
        acc[mi][ni] = __builtin_amdgcn_mfma_f32_16x16x32_bf16(af[mi], bf[ni], acc[mi][ni], 0, 0, 0);
    if (k0 + 32 < K) swrite(cur ^ 1, k0 + 32, ca0, ca1, cb0, cb1);
    __syncthreads();
    ca0 = na0; ca1 = na1; cb0 = nb0; cb1 = nb1;
    cur ^= 1;
  }

#pragma unroll
  for (int mi = 0; mi < 4; ++mi) {
#pragma unroll
    for (int j = 0; j < 4; ++j) {
      const int m = bm + wr * 64 + mi * 16 + (lane >> 4) * 4 + j;
#pragma unroll
      for (int ni = 0; ni < 4; ++ni) {
        const int col = bn + wc * 64 + ni * 16 + lr;
        float v = acc[mi][ni][j] + bias[col];
        if (MODE == 1) v = geluf(v);
        if (MODE == 0 || MODE == 1) {
          ((unsigned short*)Cv)[(size_t)m * ldc + col] = f2bf(v);
        } else if (MODE == 2) {
          const int pq = m >> 3, s = m & 7;
          const int fs = flip ? (7 - s) : s;
          unsigned short* p = (unsigned short*)Cv + (size_t)(pq * 8 + fs) * ldc + col;
          *p = f2bf(bf2f(*p) + v);
        } else {  // MODE 6
          const int pq = m >> 3, s = m & 7;
          const int fs = flip ? (7 - s) : s;
          const size_t ix = (size_t)(pq * 8 + fs) * ldc + col;
          ((unsigned short*)Cv)[ix] = f2bf(bf2f(Cin[ix]) + v);
        }
      }
    }
  }
}

// ---------- causal depthwise conv(4) + silu: xz(xm half, stride 1024) -> xa bf16 ----------
__global__ __launch_bounds__(512) void conv_k(const unsigned short* __restrict__ xz,
                                              const float* __restrict__ cw,
                                              const float* __restrict__ cb,
                                              unsigned short* __restrict__ xa) {
  const int p = blockIdx.x;
  const int c = threadIdx.x;
  float v[8];
#pragma unroll
  for (int s = 0; s < 8; ++s) v[s] = bf2f(xz[(size_t)(p * 8 + s) * 1024 + c]);
  const float4 cwv = *(const float4*)(cw + c * 4);
  const float cbv = cb[c];
#pragma unroll
  for (int s = 0; s < 8; ++s) {
    float acc = cbv + v[s] * cwv.w;
    if (s >= 1) acc += v[s - 1] * cwv.z;
    if (s >= 2) acc += v[s - 2] * cwv.y;
    if (s >= 3) acc += v[s - 3] * cwv.x;
    xa[(size_t)(p * 8 + s) * 512 + c] = f2bf(silu_fast(acc));
  }
}

// ---------- mLSTM: factored-exp form, conv recomputed in-register, fast-math ----------
// h_s = sum_t qk_t*E_t*v_t / (max(|sum_t qk_t*E_t|, exp(-lfc_s)) + 1e-6)
// with E_t = exp(ig_t - lfc_t). Denominator >= 1 here (lfc<=0) so eps rescale is immaterial.
__global__ __launch_bounds__(256) void mlstm_k(unsigned short* __restrict__ xab,
                                               const unsigned short* __restrict__ xz,
                                               const unsigned short* __restrict__ gateb,
                                               const float* __restrict__ cw,
                                               const float* __restrict__ cb,
                                               const float* __restrict__ qw,
                                               const float* __restrict__ kw,
                                               const float* __restrict__ onw,
                                               const float* __restrict__ onb,
                                               const float* __restrict__ skp) {
  const int p = blockIdx.x * 2 + (threadIdx.x >> 7);
  const int n = threadIdx.x & 127;
  float kwv[4][4], cwt[4][4];
  float cbv[4];
#pragma unroll
  for (int e = 0; e < 4; ++e) {
    float4 k4 = *(const float4*)(kw + n * 16 + e * 4);
    kwv[e][0] = k4.x; kwv[e][1] = k4.y; kwv[e][2] = k4.z; kwv[e][3] = k4.w;
    float4 c4 = *(const float4*)(cw + (n * 4 + e) * 4);
    cwt[e][0] = c4.x; cwt[e][1] = c4.y; cwt[e][2] = c4.z; cwt[e][3] = c4.w;
  }
  {
    float4 cb4 = *(const float4*)(cb + n * 4);
    cbv[0] = cb4.x; cbv[1] = cb4.y; cbv[2] = cb4.z; cbv[3] = cb4.w;
  }
  float xa[8][4], k[8][4], v[8][4], E[8], en[8];
  float run = 0.f;
#pragma unroll
  for (int s = 0; s < 8; ++s) {
    const size_t row = (size_t)(p * 8 + s);
    ushort4 v4 = *(const ushort4*)(xz + row * 1024 + n * 4);
    v[s][0] = bf2f(v4.x); v[s][1] = bf2f(v4.y); v[s][2] = bf2f(v4.z); v[s][3] = bf2f(v4.w);
    // causal conv(4) + silu, rounded to bf16 (matches conv_k output consumed by gates GEMM)
#pragma unroll
    for (int e = 0; e < 4; ++e) {
      float a = cbv[e] + v[s][e] * cwt[e][3];
      if (s >= 1) a += v[s - 1][e] * cwt[e][2];
      if (s >= 2) a += v[s - 2][e] * cwt[e][1];
      if (s >= 3) a += v[s - 3][e] * cwt[e][0];
      xa[s][e] = bf2f(f2bf(silu_fast(a)));
    }
#pragma unroll
    for (int e = 0; e < 4; ++e)
      k[s][e] = xa[s][0] * kwv[e][0] + xa[s][1] * kwv[e][1] + xa[s][2] * kwv[e][2] + xa[s][3] * kwv[e][3];
    const ushort2 g2 = *(const ushort2*)(gateb + row * 256 + n * 2);
    const float igs = bf2f(g2.x);
    const float f = bf2f(g2.y);
    const float ls = fminf(f, 0.f) - __logf(1.0f + __expf(-fabsf(f)));
    run += ls;
    E[s] = __expf(igs - run);
    en[s] = __expf(-run);
  }
  float qwv[4][4];
#pragma unroll
  for (int e = 0; e < 4; ++e) {
    float4 q4 = *(const float4*)(qw + n * 16 + e * 4);
    qwv[e][0] = q4.x; qwv[e][1] = q4.y; qwv[e][2] = q4.z; qwv[e][3] = q4.w;
  }
  const float4 onwv = *(const float4*)(onw + n * 4);
  const float4 onbv = *(const float4*)(onb + n * 4);
  const float4 skv = *(const float4*)(skp + n * 4);
#pragma unroll
  for (int s = 0; s < 8; ++s) {
    float q0, q1, q2, q3;
    q0 = xa[s][0] * qwv[0][0] + xa[s][1] * qwv[0][1] + xa[s][2] * qwv[0][2] + xa[s][3] * qwv[0][3];
    q1 = xa[s][0] * qwv[1][0] + xa[s][1] * qwv[1][1] + xa[s][2] * qwv[1][2] + xa[s][3] * qwv[1][3];
    q2 = xa[s][0] * qwv[2][0] + xa[s][1] * qwv[2][1] + xa[s][2] * qwv[2][2] + xa[s][3] * qwv[2][3];
    q3 = xa[s][0] * qwv[3][0] + xa[s][1] * qwv[3][1] + xa[s][2] * qwv[3][2] + xa[s][3] * qwv[3][3];
    float csum = 0.f;
    float o0 = 0, o1 = 0, o2 = 0, o3 = 0;
#pragma unroll
    for (int t = 0; t < 8; ++t)
      if (t <= s) {
        const float qkd = (q0 * k[t][0] + q1 * k[t][1] + q2 * k[t][2] + q3 * k[t][3]) * 0.5f;
        const float cc = qkd * E[t];
        csum += cc;
        o0 += cc * v[t][0]; o1 += cc * v[t][1]; o2 += cc * v[t][2]; o3 += cc * v[t][3];
      }
    const float inv = fast_rcp(fmaxf(fabsf(csum), en[s]) + 1e-6f);
    o0 *= inv; o1 *= inv; o2 *= inv; o3 *= inv;
    const float mu = 0.25f * (o0 + o1 + o2 + o3);
    const float d0 = o0 - mu, d1 = o1 - mu, d2 = o2 - mu, d3 = o3 - mu;
    const float var = 0.25f * (d0 * d0 + d1 * d1 + d2 * d2 + d3 * d3);
    const float r = __builtin_amdgcn_rsqf(var + 1e-5f);
    const size_t row = (size_t)(p * 8 + s);
    ushort4 z4 = *(const ushort4*)(xz + row * 1024 + 512 + n * 4);
    ushort4 ge;
    ge.x = f2bf((d0 * r * onwv.x + onbv.x + skv.x * xa[s][0]) * silu_fast(bf2f(z4.x)));
    ge.y = f2bf((d1 * r * onwv.y + onbv.y + skv.y * xa[s][1]) * silu_fast(bf2f(z4.y)));
    ge.z = f2bf((d2 * r * onwv.z + onbv.z + skv.z * xa[s][2]) * silu_fast(bf2f(z4.z)));
    ge.w = f2bf((d3 * r * onwv.w + onbv.w + skv.w * xa[s][3]) * silu_fast(bf2f(z4.w)));
    *(ushort4*)(xab + row * 512 + n * 4) = ge;
  }
}

extern "C" void kernel_launch(void* const* d_in, const int* in_sizes, int n_in,
                              void* d_out, int out_size, void* d_ws, size_t ws_size,
                              hipStream_t stream) {
  const float* x = (const float*)d_in[0];
  const float* fc1w = (const float*)d_in[1];
  const float* fc1b = (const float*)d_in[2];
  const float* fc2w = (const float*)d_in[3];
  const float* fc2b = (const float*)d_in[4];
  const float* ofc1w = (const float*)d_in[5];
  const float* ofc1b = (const float*)d_in[6];
  const float* ofc2w = (const float*)d_in[7];
  const float* ofc2b = (const float*)d_in[8];
  const float* nw = (const float*)d_in[9];
  const float* nb = (const float*)d_in[10];
  const float* upw = (const float*)d_in[11];
  const float* upb = (const float*)d_in[12];
  const float* cw = (const float*)d_in[13];
  const float* cb = (const float*)d_in[14];
  const float* qw = (const float*)d_in[15];
  const float* kw = (const float*)d_in[16];
  const float* igw = (const float*)d_in[17];
  const float* igbias = (const float*)d_in[18];
  const float* fgw = (const float*)d_in[19];
  const float* fgbias = (const float*)d_in[20];
  const float* onw = (const float*)d_in[21];
  const float* onb = (const float*)d_in[22];
  const float* skp = (const float*)d_in[23];
  const float* dww = (const float*)d_in[24];
  const float* dwb = (const float*)d_in[25];
  float* out = (float*)d_out;

  // workspace layout (byte offsets), ~114.3 MB total
  char* ws = (char*)d_ws;
  unsigned short* hbuf = (unsigned short*)ws;               // M*256 bf16  13,107,200
  unsigned short* bufD = (unsigned short*)(ws + 13107200);  // M*256 bf16  13,107,200
  unsigned short* bufA = (unsigned short*)(ws + 26214400);  // M*128 bf16   6,553,600
  unsigned short* xz = (unsigned short*)(ws + 32768000);    // M*1024 bf16 52,428,800
  unsigned short* hmirror = xz;                             // M*256 bf16 (after mlstm layer 1)
  unsigned short* xab = (unsigned short*)(ws + 85196800);   // M*512 bf16  26,214,400
  unsigned short* xflat = xab;                              // alias: dead before conv
  unsigned short* wb = (unsigned short*)(ws + 111411200);   // WB_ELEMS bf16 = 2,916,352
  float* gbias = (float*)(ws + 111411200 + 2916352);        // 512 f32
  // end: 114,329,600

  wprep<<<dim3(5186), 256, 0, stream>>>(fc1w, fc2w, ofc1w, ofc2w, upw, dww, igw, fgw, qw, kw,
                                        igbias, fgbias, wb, gbias);

  dim3 tb(32, 8);
  trans_in<<<dim3(50, 32, 2), tb, 0, stream>>>(x, xflat);
  // in-MLP
  mgemm<1, 0><<<dim3(1, 200), 256, 0, stream>>>(xflat, 128, xflat, 128, 128, wb + OFF_FC1, 128,
                                                fc1b, nullptr, bufA, 128, 128, 0,
                                                nullptr, nullptr);
  mgemm<0, 0><<<dim3(2, 200), 256, 0, stream>>>(bufA, 128, bufA, 128, 128, wb + OFF_FC2, 128,
                                                fc2b, nullptr, hbuf, 256, 128, 0,
                                                nullptr, nullptr);

  for (int i = 0; i < 2; ++i) {
    // up-proj with fused flip+LayerNorm on A: hbuf -> xz = [xm | z]
    mgemm<0, 1><<<dim3(8, 200), 256, 0, stream>>>(hbuf, 256, hbuf, 256, 256,
                                                  wb + OFF_UP + (size_t)i * 262144, 256,
                                                  upb + i * 1024, nullptr, xz, 1024, 256, i,
                                                  nw + i * 256, nb + i * 256);
    conv_k<<<dim3(NPOS), 512, 0, stream>>>(xz, cw + i * 2048, cb + i * 512, xab);
    // gates: A = [xa (512) | xm (512)], K=1024, N=256 (interleaved ig/fg) -> bufD
    mgemm<0, 0><<<dim3(2, 200), 256, 0, stream>>>(xab, 512, xz, 1024, 512,
                                                  wb + OFF_GW + (size_t)i * 262144, 1024,
                                                  gbias + i * 256, nullptr, bufD, 256, 1024, 0,
                                                  nullptr, nullptr);
    mlstm_k<<<dim3(1600), 256, 0, stream>>>(xab, xz, bufD, cw + i * 2048, cb + i * 512,
                                            qw + i * 2048, kw + i * 2048,
                                            onw + i * 512, onb + i * 512, skp + i * 512);
    if (i == 0) {
      mgemm<2, 0><<<dim3(2, 200), 256, 0, stream>>>(xab, 512, xab, 512, 512, wb + OFF_DW, 512,
                                                    dwb, nullptr, hbuf, 256, 512, 0,
                                                    nullptr, nullptr);
    } else {
      mgemm<6, 0><<<dim3(2, 200), 256, 0, stream>>>(xab, 512, xab, 512, 512,
                                                    wb + OFF_DW + 131072, 512, dwb + 256,
                                                    hbuf, hmirror, 256, 512, 1,
                                                    nullptr, nullptr);
    }
  }

  // out-MLP
  mgemm<1, 0><<<dim3(2, 200), 256, 0, stream>>>(hmirror, 256, hmirror, 256, 256, wb + OFF_OFC1,
                                                256, ofc1b, nullptr, bufD, 256, 256, 0,
                                                nullptr, nullptr);
  mgemm<0, 0><<<dim3(1, 200), 256, 0, stream>>>(bufD, 256, bufD, 256, 256, wb + OFF_OFC2, 256,
                                                ofc2b, nullptr, bufA, 128, 256, 0,
                                                nullptr, nullptr);
  trans_out<<<dim3(50, 32, 2), tb, 0, stream>>>(x, bufA, out);
}

// Round 13
// 315.876 us; speedup vs baseline: 1.0663x; 1.0663x over previous
//
#include <hip/hip_runtime.h>
#include <cstddef>
#include <cstdint>

// B=2, NF=8(seq), DIM=128, HW=1600 -> Bp=3200 positions, M=25600 token rows
// HID=256, INNER=512, NH=128, DH=4

#define NPOS 3200
#define MTOK 25600

typedef __attribute__((ext_vector_type(8))) short short8;
typedef __attribute__((ext_vector_type(8))) unsigned short u16x8;
typedef __attribute__((ext_vector_type(4))) float f32x4;

__device__ __forceinline__ float bf2f(unsigned short u) {
  union { uint32_t i; float f; } v; v.i = ((uint32_t)u) << 16; return v.f;
}
__device__ __forceinline__ unsigned short f2bf(float f) {
  union { float f; uint32_t i; } v; v.f = f;
  uint32_t r = (v.i + 0x7fffu + ((v.i >> 16) & 1u)) >> 16;
  return (unsigned short)r;
}
__device__ __forceinline__ float geluf(float x) {
  return 0.5f * x * (1.0f + erff(x * 0.70710678118654752f));
}
__device__ __forceinline__ float fast_rcp(float x) { return __builtin_amdgcn_rcpf(x); }
__device__ __forceinline__ float silu_fast(float x) {
  return x * fast_rcp(1.0f + __expf(-x));
}

// bf16 weight-buffer offsets (elements)
#define OFF_FC1 0
#define OFF_FC2 16384
#define OFF_OFC1 49152
#define OFF_OFC2 114688
#define OFF_UP 147456
#define OFF_DW 671744
#define OFF_GW 933888
#define WB_ELEMS 1458176

// ---------- merged weight prep (gate rows interleaved: col 2n=ig_n, 2n+1=fg_n) ----------
__global__ __launch_bounds__(256) void wprep(const float* __restrict__ fc1w,
                                             const float* __restrict__ fc2w,
                                             const float* __restrict__ ofc1w,
                                             const float* __restrict__ ofc2w,
                                             const float* __restrict__ upw,
                                             const float* __restrict__ dww,
                                             const float* __restrict__ igw,
                                             const float* __restrict__ fgw,
                                             const float* __restrict__ qw,
                                             const float* __restrict__ kw,
                                             const float* __restrict__ igbias,
                                             const float* __restrict__ fgbias,
                                             unsigned short* __restrict__ wb,
                                             float* __restrict__ gbias) {
  int i = blockIdx.x * 256 + threadIdx.x;
  if (i < 16384) { wb[OFF_FC1 + i] = f2bf(fc1w[i]); return; }
  i -= 16384;
  if (i < 32768) { wb[OFF_FC2 + i] = f2bf(fc2w[i]); return; }
  i -= 32768;
  if (i < 65536) { wb[OFF_OFC1 + i] = f2bf(ofc1w[i]); return; }
  i -= 65536;
  if (i < 32768) { wb[OFF_OFC2 + i] = f2bf(ofc2w[i]); return; }
  i -= 32768;
  if (i < 524288) { wb[OFF_UP + i] = f2bf(upw[i]); return; }
  i -= 524288;
  if (i < 262144) { wb[OFF_DW + i] = f2bf(dww[i]); return; }
  i -= 262144;
  if (i < 262144) {  // gx part of gate weight: W[2*row+gate, 512 + c]
    const int l = i >> 17;
    const int r = i & 131071;
    const int gate = r >> 16;
    const int rr = r & 65535;
    const int row = rr >> 9, c = rr & 511;
    const float* src = (gate ? fgw : igw) + (size_t)l * 196608 + (size_t)row * 1536 + 1024 + c;
    wb[OFF_GW + (size_t)l * 262144 + (size_t)(2 * row + gate) * 1024 + 512 + c] = f2bf(*src);
    return;
  }
  i -= 262144;
  if (i < 131072) {  // fold part: W[2*jj+gate, c], c<512
    const int l = i >> 16;
    const int r = i & 65535;
    const int jj = r >> 9, c = r & 511;
    const int n = c >> 2, d = c & 3;
    const float* igp = igw + (size_t)l * 196608;
    const float* fgp = fgw + (size_t)l * 196608;
    const float* qp = qw + l * 2048;
    const float* kp = kw + l * 2048;
    float si = 0.f, sf = 0.f;
#pragma unroll
    for (int e = 0; e < 4; ++e) {
      const float qv = qp[n * 16 + e * 4 + d];
      const float kv = kp[n * 16 + e * 4 + d];
      si += igp[jj * 1536 + n * 4 + e] * qv + igp[jj * 1536 + 512 + n * 4 + e] * kv;
      sf += fgp[jj * 1536 + n * 4 + e] * qv + fgp[jj * 1536 + 512 + n * 4 + e] * kv;
    }
    wb[OFF_GW + (size_t)l * 262144 + (size_t)(2 * jj) * 1024 + c] = f2bf(si);
    wb[OFF_GW + (size_t)l * 262144 + (size_t)(2 * jj + 1) * 1024 + c] = f2bf(sf);
    return;
  }
  i -= 131072;
  if (i < 512) {
    const int l = i >> 8, c = i & 255;
    gbias[l * 256 + c] = (c & 1) ? fgbias[l * 128 + (c >> 1)] : igbias[l * 128 + (c >> 1)];
  }
}

// ---------- transpose in: x (B,1024,1600) fp32 -> xflat (B*1600, 1024) bf16 ----------
__global__ __launch_bounds__(256) void trans_in(const float* __restrict__ x,
                                                unsigned short* __restrict__ xf) {
  __shared__ float tile[32][33];
  const int b = blockIdx.z;
  const int hw0 = blockIdx.x * 32;
  const int sc0 = blockIdx.y * 32;
  const int tx = threadIdx.x, ty = threadIdx.y;  // 32 x 8
#pragma unroll
  for (int i = 0; i < 32; i += 8)
    tile[ty + i][tx] = x[((size_t)b * 1024 + sc0 + ty + i) * 1600 + hw0 + tx];
  __syncthreads();
#pragma unroll
  for (int i = 0; i < 32; i += 8)
    xf[((size_t)b * 1600 + hw0 + ty + i) * 1024 + sc0 + tx] = f2bf(tile[tx][ty + i]);
}

// ---------- transpose out ----------
__global__ __launch_bounds__(256) void trans_out(const float* __restrict__ x,
                                                 const unsigned short* __restrict__ o,
                                                 float* __restrict__ out) {
  __shared__ float tile[32][33];
  const int b = blockIdx.z;
  const int hw0 = blockIdx.x * 32;
  const int sc0 = blockIdx.y * 32;
  const int tx = threadIdx.x, ty = threadIdx.y;
#pragma unroll
  for (int i = 0; i < 32; i += 8)
    tile[ty + i][tx] = bf2f(o[((size_t)b * 1600 + hw0 + ty + i) * 1024 + sc0 + tx]);
  __syncthreads();
#pragma unroll
  for (int i = 0; i < 32; i += 8) {
    size_t idx = ((size_t)b * 1024 + sc0 + ty + i) * 1600 + hw0 + tx;
    out[idx] = x[idx] + tile[tx][ty + i];
  }
}

// ---------- MFMA bf16 GEMM: reg-staged, dbuf LDS, 1 barrier/step, XCD swizzle ----------
// A split over K: cols [0,KA) from A (lda), [KA,K) from A2 (lda2). W: bf16 (N x ldw).
// Tile 128 x TN (TN=128 or 64). 4 waves: 2x2, each 64 x TN/2. BK=32.
// LDS k-planes padded (129/65 rows) so plane stride % 128B == 16B -> banks decorrelated.
// MODE 0: C_bf16 = v + bias
// MODE 1: C_bf16 = gelu(v + bias)
// MODE 2: C_bf16[flip-row] += v + bias         (RMW bf16)
// MODE 6: C_bf16[flip-row] = Cin_bf16[flip-row] + v + bias
template <int MODE, int TN>
__global__ __launch_bounds__(256) void mgemm(const unsigned short* __restrict__ A, int lda,
                                             const unsigned short* __restrict__ A2, int lda2,
                                             int KA,
                                             const unsigned short* __restrict__ W, int ldw,
                                             const float* __restrict__ bias,
                                             const unsigned short* __restrict__ Cin,
                                             void* __restrict__ Cv, int ldc, int K,
                                             int flip) {
  constexpr int NI = TN / 32;          // col fragments per wave
  constexpr int BROWS = (TN == 128) ? 129 : 65;
  __shared__ __align__(16) unsigned short Als[2][4][129][8];
  __shared__ __align__(16) unsigned short Bls[2][4][BROWS][8];
  const int t = threadIdx.x;
  const int lane = t & 63, wid = t >> 6;
  const int wr = wid >> 1, wc = wid & 1;
  // XCD-aware bijective chunked swizzle (all grids: nwg % 8 == 0, gridDim.x pow2)
  const int nwg = gridDim.x * gridDim.y;
  const int bid = blockIdx.y * gridDim.x + blockIdx.x;
  const int q = nwg >> 3, r = nwg & 7;
  const int xcd = bid & 7, idx = bid >> 3;
  const int swz = (xcd < r ? xcd * (q + 1) : r * (q + 1) + (xcd - r) * q) + idx;
  const int bx = swz & (gridDim.x - 1);
  const int by = swz >> (31 - __builtin_clz(gridDim.x));
  const int bm = by * 128, bn = bx * TN;
  const int srow = t >> 1;       // A: 0..127
  const int skh = (t & 1) << 4;  // A: 0 or 16
  const int ch = skh >> 3;       // A: 0 or 2
  const int srB = (TN == 128) ? srow : (t >> 2);        // B rows
  const int chB = (TN == 128) ? ch : (t & 3);           // B k-chunk
  const int skB = (TN == 128) ? skh : ((t & 3) << 3);   // B k-offset
  const int kc = lane >> 4;
  const int lr = lane & 15;
  f32x4 acc[4][NI] = {};
  const unsigned short* Wp = W + (size_t)(bn + srB) * ldw + skB;

  auto gload = [&](int k0, u16x8& a0, u16x8& a1, u16x8& b0, u16x8& b1) {
    const unsigned short* Ab;
    int kk, ldA;
    if (k0 < KA) { Ab = A; kk = k0; ldA = lda; }
    else { Ab = A2; kk = k0 - KA; ldA = lda2; }
    const unsigned short* ap = Ab + (size_t)(bm + srow) * ldA + kk + skh;
    a0 = *(const u16x8*)ap;
    a1 = *(const u16x8*)(ap + 8);
    b0 = *(const u16x8*)(Wp + k0);
    if (TN == 128) b1 = *(const u16x8*)(Wp + k0 + 8);
  };
  auto swrite = [&](int buf, u16x8 a0, u16x8 a1, u16x8 b0, u16x8 b1) {
    *(u16x8*)&Als[buf][ch][srow][0] = a0;
    *(u16x8*)&Als[buf][ch + 1][srow][0] = a1;
    *(u16x8*)&Bls[buf][chB][srB][0] = b0;
    if (TN == 128) *(u16x8*)&Bls[buf][chB + 1][srB][0] = b1;
  };

  u16x8 ca0, ca1, cb0, cb1;
  gload(0, ca0, ca1, cb0, cb1);
  swrite(0, ca0, ca1, cb0, cb1);
  if (K > 32) gload(32, ca0, ca1, cb0, cb1);
  __syncthreads();
  int cur = 0;
  for (int k0 = 0; k0 < K; k0 += 32) {
    u16x8 na0, na1, nb0, nb1;
    if (k0 + 64 < K) gload(k0 + 64, na0, na1, nb0, nb1);  // issue early, consumed next step
    short8 af[4], bf[NI];
#pragma unroll
    for (int mi = 0; mi < 4; ++mi)
      af[mi] = *(const short8*)&Als[cur][kc][wr * 64 + mi * 16 + lr][0];
#pragma unroll
    for (int ni = 0; ni < NI; ++ni)
      bf[ni] = *(const short8*)&Bls[cur][kc][wc * (TN / 2) + ni * 16 + lr][0];
#pragma unroll
    for (int mi = 0; mi < 4; ++mi)
#pragma unroll
      for (int ni = 0; ni < NI; ++ni)
        acc[mi][ni] = __builtin_amdgcn_mfma_f32_16x16x32_bf16(af[mi], bf[ni], acc[mi][ni], 0, 0, 0);
    if (k0 + 32 < K) swrite(cur ^ 1, ca0, ca1, cb0, cb1);
    __syncthreads();
    ca0 = na0; ca1 = na1; cb0 = nb0; cb1 = nb1;
    cur ^= 1;
  }

#pragma unroll
  for (int mi = 0; mi < 4; ++mi) {
#pragma unroll
    for (int j = 0; j < 4; ++j) {
      const int m = bm + wr * 64 + mi * 16 + (lane >> 4) * 4 + j;
#pragma unroll
      for (int ni = 0; ni < NI; ++ni) {
        const int col = bn + wc * (TN / 2) + ni * 16 + lr;
        float v = acc[mi][ni][j] + bias[col];
        if (MODE == 1) v = geluf(v);
        if (MODE == 0 || MODE == 1) {
          ((unsigned short*)Cv)[(size_t)m * ldc + col] = f2bf(v);
        } else if (MODE == 2) {
          const int pq = m >> 3, s = m & 7;
          const int fs = flip ? (7 - s) : s;
          unsigned short* p = (unsigned short*)Cv + (size_t)(pq * 8 + fs) * ldc + col;
          *p = f2bf(bf2f(*p) + v);
        } else {  // MODE 6
          const int pq = m >> 3, s = m & 7;
          const int fs = flip ? (7 - s) : s;
          const size_t ix = (size_t)(pq * 8 + fs) * ldc + col;
          ((unsigned short*)Cv)[ix] = f2bf(bf2f(Cin[ix]) + v);
        }
      }
    }
  }
}

// ---------- layernorm (bf16 in) with flip-on-read: y bf16 ----------
__global__ __launch_bounds__(256) void ln_k(const unsigned short* __restrict__ h,
                                            const float* __restrict__ w,
                                            const float* __restrict__ b,
                                            unsigned short* __restrict__ y, int flip) {
  const int m = blockIdx.x * 4 + (threadIdx.x >> 6);
  const int lane = threadIdx.x & 63;
  const int p = m >> 3, s = m & 7;
  const int ss = flip ? (7 - s) : s;
  const unsigned short* row = h + (size_t)(p * 8 + ss) * 256;
  ushort4 u4 = *(const ushort4*)(row + lane * 4);
  float v0 = bf2f(u4.x), v1 = bf2f(u4.y), v2 = bf2f(u4.z), v3 = bf2f(u4.w);
  float sum = v0 + v1 + v2 + v3;
  float sq = v0 * v0 + v1 * v1 + v2 * v2 + v3 * v3;
#pragma unroll
  for (int o = 32; o > 0; o >>= 1) {
    sum += __shfl_xor(sum, o);
    sq += __shfl_xor(sq, o);
  }
  float mu = sum * (1.f / 256.f);
  float var = sq * (1.f / 256.f) - mu * mu;
  float r = rsqrtf(var + 1e-5f);
  float4 wv = *(const float4*)(w + lane * 4);
  float4 bv = *(const float4*)(b + lane * 4);
  ushort4 o_;
  o_.x = f2bf((v0 - mu) * r * wv.x + bv.x);
  o_.y = f2bf((v1 - mu) * r * wv.y + bv.y);
  o_.z = f2bf((v2 - mu) * r * wv.z + bv.z);
  o_.w = f2bf((v3 - mu) * r * wv.w + bv.w);
  *(ushort4*)(y + (size_t)m * 256 + lane * 4) = o_;
}

// ---------- causal depthwise conv(4) + silu: xz(xm half, stride 1024) -> xa bf16 ----------
__global__ __launch_bounds__(512) void conv_k(const unsigned short* __restrict__ xz,
                                              const float* __restrict__ cw,
                                              const float* __restrict__ cb,
                                              unsigned short* __restrict__ xa) {
  const int p = blockIdx.x;
  const int c = threadIdx.x;
  float v[8];
#pragma unroll
  for (int s = 0; s < 8; ++s) v[s] = bf2f(xz[(size_t)(p * 8 + s) * 1024 + c]);
  const float4 cwv = *(const float4*)(cw + c * 4);
  const float cbv = cb[c];
#pragma unroll
  for (int s = 0; s < 8; ++s) {
    float acc = cbv + v[s] * cwv.w;
    if (s >= 1) acc += v[s - 1] * cwv.z;
    if (s >= 2) acc += v[s - 2] * cwv.y;
    if (s >= 3) acc += v[s - 3] * cwv.x;
    xa[(size_t)(p * 8 + s) * 512 + c] = f2bf(silu_fast(acc));
  }
}

// ---------- mLSTM: factored-exp form, conv recomputed in-register, fast-math ----------
// h_s = sum_t qk_t*E_t*v_t / (max(|sum_t qk_t*E_t|, exp(-lfc_s)) + 1e-6)
// with E_t = exp(ig_t - lfc_t). Denominator >= 1 here (lfc<=0) so eps rescale is immaterial.
__global__ __launch_bounds__(256) void mlstm_k(unsigned short* __restrict__ xab,
                                               const unsigned short* __restrict__ xz,
                                               const unsigned short* __restrict__ gateb,
                                               const float* __restrict__ cw,
                                               const float* __restrict__ cb,
                                               const float* __restrict__ qw,
                                               const float* __restrict__ kw,
                                               const float* __restrict__ onw,
                                               const float* __restrict__ onb,
                                               const float* __restrict__ skp) {
  const int p = blockIdx.x * 2 + (threadIdx.x >> 7);
  const int n = threadIdx.x & 127;
  float kwv[4][4], cwt[4][4];
  float cbv[4];
#pragma unroll
  for (int e = 0; e < 4; ++e) {
    float4 k4 = *(const float4*)(kw + n * 16 + e * 4);
    kwv[e][0] = k4.x; kwv[e][1] = k4.y; kwv[e][2] = k4.z; kwv[e][3] = k4.w;
    float4 c4 = *(const float4*)(cw + (n * 4 + e) * 4);
    cwt[e][0] = c4.x; cwt[e][1] = c4.y; cwt[e][2] = c4.z; cwt[e][3] = c4.w;
  }
  {
    float4 cb4 = *(const float4*)(cb + n * 4);
    cbv[0] = cb4.x; cbv[1] = cb4.y; cbv[2] = cb4.z; cbv[3] = cb4.w;
  }
  float xa[8][4], k[8][4], v[8][4], E[8], en[8];
  float run = 0.f;
#pragma unroll
  for (int s = 0; s < 8; ++s) {
    const size_t row = (size_t)(p * 8 + s);
    ushort4 v4 = *(const ushort4*)(xz + row * 1024 + n * 4);
    v[s][0] = bf2f(v4.x); v[s][1] = bf2f(v4.y); v[s][2] = bf2f(v4.z); v[s][3] = bf2f(v4.w);
    // causal conv(4) + silu, rounded to bf16 (matches conv_k output consumed by gates GEMM)
#pragma unroll
    for (int e = 0; e < 4; ++e) {
      float a = cbv[e] + v[s][e] * cwt[e][3];
      if (s >= 1) a += v[s - 1][e] * cwt[e][2];
      if (s >= 2) a += v[s - 2][e] * cwt[e][1];
      if (s >= 3) a += v[s - 3][e] * cwt[e][0];
      xa[s][e] = bf2f(f2bf(silu_fast(a)));
    }
#pragma unroll
    for (int e = 0; e < 4; ++e)
      k[s][e] = xa[s][0] * kwv[e][0] + xa[s][1] * kwv[e][1] + xa[s][2] * kwv[e][2] + xa[s][3] * kwv[e][3];
    const ushort2 g2 = *(const ushort2*)(gateb + row * 256 + n * 2);
    const float igs = bf2f(g2.x);
    const float f = bf2f(g2.y);
    const float ls = fminf(f, 0.f) - __logf(1.0f + __expf(-fabsf(f)));
    run += ls;
    E[s] = __expf(igs - run);
    en[s] = __expf(-run);
  }
  float qwv[4][4];
#pragma unroll
  for (int e = 0; e < 4; ++e) {
    float4 q4 = *(const float4*)(qw + n * 16 + e * 4);
    qwv[e][0] = q4.x; qwv[e][1] = q4.y; qwv[e][2] = q4.z; qwv[e][3] = q4.w;
  }
  const float4 onwv = *(const float4*)(onw + n * 4);
  const float4 onbv = *(const float4*)(onb + n * 4);
  const float4 skv = *(const float4*)(skp + n * 4);
#pragma unroll
  for (int s = 0; s < 8; ++s) {
    float q0, q1, q2, q3;
    q0 = xa[s][0] * qwv[0][0] + xa[s][1] * qwv[0][1] + xa[s][2] * qwv[0][2] + xa[s][3] * qwv[0][3];
    q1 = xa[s][0] * qwv[1][0] + xa[s][1] * qwv[1][1] + xa[s][2] * qwv[1][2] + xa[s][3] * qwv[1][3];
    q2 = xa[s][0] * qwv[2][0] + xa[s][1] * qwv[2][1] + xa[s][2] * qwv[2][2] + xa[s][3] * qwv[2][3];
    q3 = xa[s][0] * qwv[3][0] + xa[s][1] * qwv[3][1] + xa[s][2] * qwv[3][2] + xa[s][3] * qwv[3][3];
    float csum = 0.f;
    float o0 = 0, o1 = 0, o2 = 0, o3 = 0;
#pragma unroll
    for (int t = 0; t < 8; ++t)
      if (t <= s) {
        const float qkd = (q0 * k[t][0] + q1 * k[t][1] + q2 * k[t][2] + q3 * k[t][3]) * 0.5f;
        const float cc = qkd * E[t];
        csum += cc;
        o0 += cc * v[t][0]; o1 += cc * v[t][1]; o2 += cc * v[t][2]; o3 += cc * v[t][3];
      }
    const float inv = fast_rcp(fmaxf(fabsf(csum), en[s]) + 1e-6f);
    o0 *= inv; o1 *= inv; o2 *= inv; o3 *= inv;
    const float mu = 0.25f * (o0 + o1 + o2 + o3);
    const float d0 = o0 - mu, d1 = o1 - mu, d2 = o2 - mu, d3 = o3 - mu;
    const float var = 0.25f * (d0 * d0 + d1 * d1 + d2 * d2 + d3 * d3);
    const float r = __builtin_amdgcn_rsqf(var + 1e-5f);
    const size_t row = (size_t)(p * 8 + s);
    ushort4 z4 = *(const ushort4*)(xz + row * 1024 + 512 + n * 4);
    ushort4 ge;
    ge.x = f2bf((d0 * r * onwv.x + onbv.x + skv.x * xa[s][0]) * silu_fast(bf2f(z4.x)));
    ge.y = f2bf((d1 * r * onwv.y + onbv.y + skv.y * xa[s][1]) * silu_fast(bf2f(z4.y)));
    ge.z = f2bf((d2 * r * onwv.z + onbv.z + skv.z * xa[s][2]) * silu_fast(bf2f(z4.z)));
    ge.w = f2bf((d3 * r * onwv.w + onbv.w + skv.w * xa[s][3]) * silu_fast(bf2f(z4.w)));
    *(ushort4*)(xab + row * 512 + n * 4) = ge;
  }
}

extern "C" void kernel_launch(void* const* d_in, const int* in_sizes, int n_in,
                              void* d_out, int out_size, void* d_ws, size_t ws_size,
                              hipStream_t stream) {
  const float* x = (const float*)d_in[0];
  const float* fc1w = (const float*)d_in[1];
  const float* fc1b = (const float*)d_in[2];
  const float* fc2w = (const float*)d_in[3];
  const float* fc2b = (const float*)d_in[4];
  const float* ofc1w = (const float*)d_in[5];
  const float* ofc1b = (const float*)d_in[6];
  const float* ofc2w = (const float*)d_in[7];
  const float* ofc2b = (const float*)d_in[8];
  const float* nw = (const float*)d_in[9];
  const float* nb = (const float*)d_in[10];
  const float* upw = (const float*)d_in[11];
  const float* upb = (const float*)d_in[12];
  const float* cw = (const float*)d_in[13];
  const float* cb = (const float*)d_in[14];
  const float* qw = (const float*)d_in[15];
  const float* kw = (const float*)d_in[16];
  const float* igw = (const float*)d_in[17];
  const float* igbias = (const float*)d_in[18];
  const float* fgw = (const float*)d_in[19];
  const float* fgbias = (const float*)d_in[20];
  const float* onw = (const float*)d_in[21];
  const float* onb = (const float*)d_in[22];
  const float* skp = (const float*)d_in[23];
  const float* dww = (const float*)d_in[24];
  const float* dwb = (const float*)d_in[25];
  float* out = (float*)d_out;

  // workspace layout (byte offsets), ~114.3 MB total
  char* ws = (char*)d_ws;
  unsigned short* hbuf = (unsigned short*)ws;               // M*256 bf16  13,107,200
  unsigned short* bufD = (unsigned short*)(ws + 13107200);  // M*256 bf16  13,107,200
  unsigned short* bufA = (unsigned short*)(ws + 26214400);  // M*128 bf16   6,553,600
  unsigned short* xz = (unsigned short*)(ws + 32768000);    // M*1024 bf16 52,428,800
  unsigned short* hmirror = xz;                             // M*256 bf16 (after mlstm layer 1)
  unsigned short* xab = (unsigned short*)(ws + 85196800);   // M*512 bf16  26,214,400
  unsigned short* xflat = xab;                              // alias: dead before conv
  unsigned short* wb = (unsigned short*)(ws + 111411200);   // WB_ELEMS bf16 = 2,916,352
  float* gbias = (float*)(ws + 111411200 + 2916352);        // 512 f32
  // end: 114,329,600

  wprep<<<dim3(5186), 256, 0, stream>>>(fc1w, fc2w, ofc1w, ofc2w, upw, dww, igw, fgw, qw, kw,
                                        igbias, fgbias, wb, gbias);

  dim3 tb(32, 8);
  trans_in<<<dim3(50, 32, 2), tb, 0, stream>>>(x, xflat);
  // in-MLP
  mgemm<1, 64><<<dim3(2, 200), 256, 0, stream>>>(xflat, 128, xflat, 128, 128, wb + OFF_FC1, 128,
                                                 fc1b, nullptr, bufA, 128, 128, 0);
  mgemm<0, 64><<<dim3(4, 200), 256, 0, stream>>>(bufA, 128, bufA, 128, 128, wb + OFF_FC2, 128,
                                                 fc2b, nullptr, hbuf, 256, 128, 0);

  for (int i = 0; i < 2; ++i) {
    ln_k<<<dim3(6400), 256, 0, stream>>>(hbuf, nw + i * 256, nb + i * 256, bufD, i);
    // up-proj, N=1024 -> xz = [xm | z]
    mgemm<0, 128><<<dim3(8, 200), 256, 0, stream>>>(bufD, 256, bufD, 256, 256,
                                                    wb + OFF_UP + (size_t)i * 262144, 256,
                                                    upb + i * 1024, nullptr, xz, 1024, 256, 0);
    conv_k<<<dim3(NPOS), 512, 0, stream>>>(xz, cw + i * 2048, cb + i * 512, xab);
    // gates: A = [xa (512) | xm (512)], K=1024, N=256 (interleaved ig/fg) -> bufD
    mgemm<0, 64><<<dim3(4, 200), 256, 0, stream>>>(xab, 512, xz, 1024, 512,
                                                   wb + OFF_GW + (size_t)i * 262144, 1024,
                                                   gbias + i * 256, nullptr, bufD, 256, 1024, 0);
    mlstm_k<<<dim3(1600), 256, 0, stream>>>(xab, xz, bufD, cw + i * 2048, cb + i * 512,
                                            qw + i * 2048, kw + i * 2048,
                                            onw + i * 512, onb + i * 512, skp + i * 512);
    if (i == 0) {
      mgemm<2, 64><<<dim3(4, 200), 256, 0, stream>>>(xab, 512, xab, 512, 512, wb + OFF_DW, 512,
                                                     dwb, nullptr, hbuf, 256, 512, 0);
    } else {
      mgemm<6, 64><<<dim3(4, 200), 256, 0, stream>>>(xab, 512, xab, 512, 512,
                                                     wb + OFF_DW + 131072, 512, dwb + 256,
                                                     hbuf, hmirror, 256, 512, 1);
    }
  }

  // out-MLP
  mgemm<1, 64><<<dim3(4, 200), 256, 0, stream>>>(hmirror, 256, hmirror, 256, 256, wb + OFF_OFC1,
                                                 256, ofc1b, nullptr, bufD, 256, 256, 0);
  mgemm<0, 64><<<dim3(2, 200), 256, 0, stream>>>(bufD, 256, bufD, 256, 256, wb + OFF_OFC2, 256,
                                                 ofc2b, nullptr, bufA, 128, 256, 0);
  trans_out<<<dim3(50, 32, 2), tb, 0, stream>>>(x, bufA, out);
}

// Round 14
// 301.489 us; speedup vs baseline: 1.1172x; 1.0477x over previous
//
#include <hip/hip_runtime.h>
#include <cstddef>
#include <cstdint>

// B=2, NF=8(seq), DIM=128, HW=1600 -> Bp=3200 positions, M=25600 token rows
// HID=256, INNER=512, NH=128, DH=4

#define NPOS 3200
#define MTOK 25600

typedef __attribute__((ext_vector_type(8))) short short8;
typedef __attribute__((ext_vector_type(8))) unsigned short u16x8;
typedef __attribute__((ext_vector_type(4))) float f32x4;

__device__ __forceinline__ float bf2f(unsigned short u) {
  union { uint32_t i; float f; } v; v.i = ((uint32_t)u) << 16; return v.f;
}
__device__ __forceinline__ unsigned short f2bf(float f) {
  union { float f; uint32_t i; } v; v.f = f;
  uint32_t r = (v.i + 0x7fffu + ((v.i >> 16) & 1u)) >> 16;
  return (unsigned short)r;
}
__device__ __forceinline__ float geluf(float x) {
  return 0.5f * x * (1.0f + erff(x * 0.70710678118654752f));
}
__device__ __forceinline__ float fast_rcp(float x) { return __builtin_amdgcn_rcpf(x); }
__device__ __forceinline__ float silu_fast(float x) {
  return x * fast_rcp(1.0f + __expf(-x));
}

// bf16 weight-buffer offsets (elements)
#define OFF_FC1 0
#define OFF_FC2 16384
#define OFF_OFC1 49152
#define OFF_OFC2 114688
#define OFF_UP 147456
#define OFF_DW 671744
#define OFF_GW 933888
#define WB_ELEMS 1458176

// ---------- merged weight prep (gate rows interleaved: col 2n=ig_n, 2n+1=fg_n) ----------
__global__ __launch_bounds__(256) void wprep(const float* __restrict__ fc1w,
                                             const float* __restrict__ fc2w,
                                             const float* __restrict__ ofc1w,
                                             const float* __restrict__ ofc2w,
                                             const float* __restrict__ upw,
                                             const float* __restrict__ dww,
                                             const float* __restrict__ igw,
                                             const float* __restrict__ fgw,
                                             const float* __restrict__ qw,
                                             const float* __restrict__ kw,
                                             const float* __restrict__ igbias,
                                             const float* __restrict__ fgbias,
                                             unsigned short* __restrict__ wb,
                                             float* __restrict__ gbias) {
  int i = blockIdx.x * 256 + threadIdx.x;
  if (i < 16384) { wb[OFF_FC1 + i] = f2bf(fc1w[i]); return; }
  i -= 16384;
  if (i < 32768) { wb[OFF_FC2 + i] = f2bf(fc2w[i]); return; }
  i -= 32768;
  if (i < 65536) { wb[OFF_OFC1 + i] = f2bf(ofc1w[i]); return; }
  i -= 65536;
  if (i < 32768) { wb[OFF_OFC2 + i] = f2bf(ofc2w[i]); return; }
  i -= 32768;
  if (i < 524288) { wb[OFF_UP + i] = f2bf(upw[i]); return; }
  i -= 524288;
  if (i < 262144) { wb[OFF_DW + i] = f2bf(dww[i]); return; }
  i -= 262144;
  if (i < 262144) {  // gx part of gate weight: W[2*row+gate, 512 + c]
    const int l = i >> 17;
    const int r = i & 131071;
    const int gate = r >> 16;
    const int rr = r & 65535;
    const int row = rr >> 9, c = rr & 511;
    const float* src = (gate ? fgw : igw) + (size_t)l * 196608 + (size_t)row * 1536 + 1024 + c;
    wb[OFF_GW + (size_t)l * 262144 + (size_t)(2 * row + gate) * 1024 + 512 + c] = f2bf(*src);
    return;
  }
  i -= 262144;
  if (i < 131072) {  // fold part: W[2*jj+gate, c], c<512
    const int l = i >> 16;
    const int r = i & 65535;
    const int jj = r >> 9, c = r & 511;
    const int n = c >> 2, d = c & 3;
    const float* igp = igw + (size_t)l * 196608;
    const float* fgp = fgw + (size_t)l * 196608;
    const float* qp = qw + l * 2048;
    const float* kp = kw + l * 2048;
    float si = 0.f, sf = 0.f;
#pragma unroll
    for (int e = 0; e < 4; ++e) {
      const float qv = qp[n * 16 + e * 4 + d];
      const float kv = kp[n * 16 + e * 4 + d];
      si += igp[jj * 1536 + n * 4 + e] * qv + igp[jj * 1536 + 512 + n * 4 + e] * kv;
      sf += fgp[jj * 1536 + n * 4 + e] * qv + fgp[jj * 1536 + 512 + n * 4 + e] * kv;
    }
    wb[OFF_GW + (size_t)l * 262144 + (size_t)(2 * jj) * 1024 + c] = f2bf(si);
    wb[OFF_GW + (size_t)l * 262144 + (size_t)(2 * jj + 1) * 1024 + c] = f2bf(sf);
    return;
  }
  i -= 131072;
  if (i < 512) {
    const int l = i >> 8, c = i & 255;
    gbias[l * 256 + c] = (c & 1) ? fgbias[l * 128 + (c >> 1)] : igbias[l * 128 + (c >> 1)];
  }
}

// ---------- transpose in: x (B,1024,1600) fp32 -> xflat (B*1600, 1024) bf16 ----------
__global__ __launch_bounds__(256) void trans_in(const float* __restrict__ x,
                                                unsigned short* __restrict__ xf) {
  __shared__ float tile[32][33];
  const int b = blockIdx.z;
  const int hw0 = blockIdx.x * 32;
  const int sc0 = blockIdx.y * 32;
  const int tx = threadIdx.x, ty = threadIdx.y;  // 32 x 8
#pragma unroll
  for (int i = 0; i < 32; i += 8)
    tile[ty + i][tx] = x[((size_t)b * 1024 + sc0 + ty + i) * 1600 + hw0 + tx];
  __syncthreads();
#pragma unroll
  for (int i = 0; i < 32; i += 8)
    xf[((size_t)b * 1600 + hw0 + ty + i) * 1024 + sc0 + tx] = f2bf(tile[tx][ty + i]);
}

// ---------- transpose out ----------
__global__ __launch_bounds__(256) void trans_out(const float* __restrict__ x,
                                                 const unsigned short* __restrict__ o,
                                                 float* __restrict__ out) {
  __shared__ float tile[32][33];
  const int b = blockIdx.z;
  const int hw0 = blockIdx.x * 32;
  const int sc0 = blockIdx.y * 32;
  const int tx = threadIdx.x, ty = threadIdx.y;
#pragma unroll
  for (int i = 0; i < 32; i += 8)
    tile[ty + i][tx] = bf2f(o[((size_t)b * 1600 + hw0 + ty + i) * 1024 + sc0 + tx]);
  __syncthreads();
#pragma unroll
  for (int i = 0; i < 32; i += 8) {
    size_t idx = ((size_t)b * 1024 + sc0 + ty + i) * 1600 + hw0 + tx;
    out[idx] = x[idx] + tile[tx][ty + i];
  }
}

// ---------- MFMA bf16 GEMM: reg-staged, double-buffered LDS, 1 barrier/step, XCD swizzle ----------
// A split over K: cols [0,KA) from A (lda), [KA,K) from A2 (lda2). W: bf16 (N x ldw).
// 128x128 tile, BK=32, 4 waves, 64x64/wave. LDS [buf][kc][row][8].
// MODE 0: C_bf16 = v + bias
// MODE 1: C_bf16 = gelu(v + bias)
// MODE 2: C_bf16[flip-row] += v + bias         (RMW bf16)
// MODE 6: C_bf16[flip-row] = Cin_bf16[flip-row] + v + bias
template <int MODE>
__global__ __launch_bounds__(256) void mgemm(const unsigned short* __restrict__ A, int lda,
                                             const unsigned short* __restrict__ A2, int lda2,
                                             int KA,
                                             const unsigned short* __restrict__ W, int ldw,
                                             const float* __restrict__ bias,
                                             const unsigned short* __restrict__ Cin,
                                             void* __restrict__ Cv, int ldc, int K,
                                             int flip) {
  __shared__ __align__(16) unsigned short Als[2][4][128][8];  // 16 KB
  __shared__ __align__(16) unsigned short Bls[2][4][128][8];  // 16 KB
  const int t = threadIdx.x;
  const int lane = t & 63, wid = t >> 6;
  const int wr = wid >> 1, wc = wid & 1;
  // XCD-aware bijective chunked swizzle (all grids here have nwg % 8 == 0, gridDim.x pow2)
  const int nwg = gridDim.x * gridDim.y;
  const int bid = blockIdx.y * gridDim.x + blockIdx.x;
  const int q = nwg >> 3, r = nwg & 7;
  const int xcd = bid & 7, idx = bid >> 3;
  const int swz = (xcd < r ? xcd * (q + 1) : r * (q + 1) + (xcd - r) * q) + idx;
  const int bx = swz & (gridDim.x - 1);
  const int by = swz >> (31 - __builtin_clz(gridDim.x));
  const int bm = by * 128, bn = bx * 128;
  const int srow = t >> 1;       // 0..127
  const int skh = (t & 1) << 4;  // 0 or 16
  const int ch = skh >> 3;       // 0 or 2
  const int kc = lane >> 4;
  const int lr = lane & 15;
  f32x4 acc[4][4] = {};
  const unsigned short* Wp = W + (size_t)(bn + srow) * ldw + skh;

  auto gload = [&](int k0, u16x8& a0, u16x8& a1, u16x8& b0, u16x8& b1) {
    const unsigned short* Ab;
    int kk, ldA;
    if (k0 < KA) { Ab = A; kk = k0; ldA = lda; }
    else { Ab = A2; kk = k0 - KA; ldA = lda2; }
    const unsigned short* ap = Ab + (size_t)(bm + srow) * ldA + kk + skh;
    a0 = *(const u16x8*)ap;
    a1 = *(const u16x8*)(ap + 8);
    b0 = *(const u16x8*)(Wp + k0);
    b1 = *(const u16x8*)(Wp + k0 + 8);
  };
  auto swrite = [&](int buf, u16x8 a0, u16x8 a1, u16x8 b0, u16x8 b1) {
    *(u16x8*)&Als[buf][ch][srow][0] = a0;
    *(u16x8*)&Als[buf][ch + 1][srow][0] = a1;
    *(u16x8*)&Bls[buf][ch][srow][0] = b0;
    *(u16x8*)&Bls[buf][ch + 1][srow][0] = b1;
  };

  u16x8 ca0, ca1, cb0, cb1;
  gload(0, ca0, ca1, cb0, cb1);
  swrite(0, ca0, ca1, cb0, cb1);
  if (K > 32) gload(32, ca0, ca1, cb0, cb1);
  __syncthreads();
  int cur = 0;
  for (int k0 = 0; k0 < K; k0 += 32) {
    u16x8 na0, na1, nb0, nb1;
    if (k0 + 64 < K) gload(k0 + 64, na0, na1, nb0, nb1);  // issue early, consumed next step
    short8 af[4], bf[4];
#pragma unroll
    for (int mi = 0; mi < 4; ++mi)
      af[mi] = *(const short8*)&Als[cur][kc][wr * 64 + mi * 16 + lr][0];
#pragma unroll
    for (int ni = 0; ni < 4; ++ni)
      bf[ni] = *(const short8*)&Bls[cur][kc][wc * 64 + ni * 16 + lr][0];
#pragma unroll
    for (int mi = 0; mi < 4; ++mi)
#pragma unroll
      for (int ni = 0; ni < 4; ++ni)
        acc[mi][ni] = __builtin_amdgcn_mfma_f32_16x16x32_bf16(af[mi], bf[ni], acc[mi][ni], 0, 0, 0);
    if (k0 + 32 < K) swrite(cur ^ 1, ca0, ca1, cb0, cb1);
    __syncthreads();
    ca0 = na0; ca1 = na1; cb0 = nb0; cb1 = nb1;
    cur ^= 1;
  }

#pragma unroll
  for (int mi = 0; mi < 4; ++mi) {
#pragma unroll
    for (int j = 0; j < 4; ++j) {
      const int m = bm + wr * 64 + mi * 16 + (lane >> 4) * 4 + j;
#pragma unroll
      for (int ni = 0; ni < 4; ++ni) {
        const int col = bn + wc * 64 + ni * 16 + lr;
        float v = acc[mi][ni][j] + bias[col];
        if (MODE == 1) v = geluf(v);
        if (MODE == 0 || MODE == 1) {
          ((unsigned short*)Cv)[(size_t)m * ldc + col] = f2bf(v);
        } else if (MODE == 2) {
          const int pq = m >> 3, s = m & 7;
          const int fs = flip ? (7 - s) : s;
          unsigned short* p = (unsigned short*)Cv + (size_t)(pq * 8 + fs) * ldc + col;
          *p = f2bf(bf2f(*p) + v);
        } else {  // MODE 6
          const int pq = m >> 3, s = m & 7;
          const int fs = flip ? (7 - s) : s;
          const size_t ix = (size_t)(pq * 8 + fs) * ldc + col;
          ((unsigned short*)Cv)[ix] = f2bf(bf2f(Cin[ix]) + v);
        }
      }
    }
  }
}

// ---------- layernorm (bf16 in) with flip-on-read: y bf16 ----------
__global__ __launch_bounds__(256) void ln_k(const unsigned short* __restrict__ h,
                                            const float* __restrict__ w,
                                            const float* __restrict__ b,
                                            unsigned short* __restrict__ y, int flip) {
  const int m = blockIdx.x * 4 + (threadIdx.x >> 6);
  const int lane = threadIdx.x & 63;
  const int p = m >> 3, s = m & 7;
  const int ss = flip ? (7 - s) : s;
  const unsigned short* row = h + (size_t)(p * 8 + ss) * 256;
  ushort4 u4 = *(const ushort4*)(row + lane * 4);
  float v0 = bf2f(u4.x), v1 = bf2f(u4.y), v2 = bf2f(u4.z), v3 = bf2f(u4.w);
  float sum = v0 + v1 + v2 + v3;
  float sq = v0 * v0 + v1 * v1 + v2 * v2 + v3 * v3;
#pragma unroll
  for (int o = 32; o > 0; o >>= 1) {
    sum += __shfl_xor(sum, o);
    sq += __shfl_xor(sq, o);
  }
  float mu = sum * (1.f / 256.f);
  float var = sq * (1.f / 256.f) - mu * mu;
  float r = rsqrtf(var + 1e-5f);
  float4 wv = *(const float4*)(w + lane * 4);
  float4 bv = *(const float4*)(b + lane * 4);
  ushort4 o_;
  o_.x = f2bf((v0 - mu) * r * wv.x + bv.x);
  o_.y = f2bf((v1 - mu) * r * wv.y + bv.y);
  o_.z = f2bf((v2 - mu) * r * wv.z + bv.z);
  o_.w = f2bf((v3 - mu) * r * wv.w + bv.w);
  *(ushort4*)(y + (size_t)m * 256 + lane * 4) = o_;
}

// ---------- causal depthwise conv(4) + silu: xz(xm half, stride 1024) -> xa bf16 ----------
__global__ __launch_bounds__(512) void conv_k(const unsigned short* __restrict__ xz,
                                              const float* __restrict__ cw,
                                              const float* __restrict__ cb,
                                              unsigned short* __restrict__ xa) {
  const int p = blockIdx.x;
  const int c = threadIdx.x;
  float v[8];
#pragma unroll
  for (int s = 0; s < 8; ++s) v[s] = bf2f(xz[(size_t)(p * 8 + s) * 1024 + c]);
  const float4 cwv = *(const float4*)(cw + c * 4);
  const float cbv = cb[c];
#pragma unroll
  for (int s = 0; s < 8; ++s) {
    float acc = cbv + v[s] * cwv.w;
    if (s >= 1) acc += v[s - 1] * cwv.z;
    if (s >= 2) acc += v[s - 2] * cwv.y;
    if (s >= 3) acc += v[s - 3] * cwv.x;
    xa[(size_t)(p * 8 + s) * 512 + c] = f2bf(silu_fast(acc));
  }
}

// ---------- mLSTM: factored-exp form, conv recomputed in-register, fast-math ----------
// h_s = sum_t qk_t*E_t*v_t / (max(|sum_t qk_t*E_t|, exp(-lfc_s)) + 1e-6)
// with E_t = exp(ig_t - lfc_t). Denominator >= 1 here (lfc<=0) so eps rescale is immaterial.
__global__ __launch_bounds__(256) void mlstm_k(unsigned short* __restrict__ xab,
                                               const unsigned short* __restrict__ xz,
                                               const unsigned short* __restrict__ gateb,
                                               const float* __restrict__ cw,
                                               const float* __restrict__ cb,
                                               const float* __restrict__ qw,
                                               const float* __restrict__ kw,
                                               const float* __restrict__ onw,
                                               const float* __restrict__ onb,
                                               const float* __restrict__ skp) {
  const int p = blockIdx.x * 2 + (threadIdx.x >> 7);
  const int n = threadIdx.x & 127;
  float kwv[4][4], cwt[4][4];
  float cbv[4];
#pragma unroll
  for (int e = 0; e < 4; ++e) {
    float4 k4 = *(const float4*)(kw + n * 16 + e * 4);
    kwv[e][0] = k4.x; kwv[e][1] = k4.y; kwv[e][2] = k4.z; kwv[e][3] = k4.w;
    float4 c4 = *(const float4*)(cw + (n * 4 + e) * 4);
    cwt[e][0] = c4.x; cwt[e][1] = c4.y; cwt[e][2] = c4.z; cwt[e][3] = c4.w;
  }
  {
    float4 cb4 = *(const float4*)(cb + n * 4);
    cbv[0] = cb4.x; cbv[1] = cb4.y; cbv[2] = cb4.z; cbv[3] = cb4.w;
  }
  float xa[8][4], k[8][4], v[8][4], E[8], en[8];
  float run = 0.f;
#pragma unroll
  for (int s = 0; s < 8; ++s) {
    const size_t row = (size_t)(p * 8 + s);
    ushort4 v4 = *(const ushort4*)(xz + row * 1024 + n * 4);
    v[s][0] = bf2f(v4.x); v[s][1] = bf2f(v4.y); v[s][2] = bf2f(v4.z); v[s][3] = bf2f(v4.w);
    // causal conv(4) + silu, rounded to bf16 (matches conv_k output consumed by gates GEMM)
#pragma unroll
    for (int e = 0; e < 4; ++e) {
      float a = cbv[e] + v[s][e] * cwt[e][3];
      if (s >= 1) a += v[s - 1][e] * cwt[e][2];
      if (s >= 2) a += v[s - 2][e] * cwt[e][1];
      if (s >= 3) a += v[s - 3][e] * cwt[e][0];
      xa[s][e] = bf2f(f2bf(silu_fast(a)));
    }
#pragma unroll
    for (int e = 0; e < 4; ++e)
      k[s][e] = xa[s][0] * kwv[e][0] + xa[s][1] * kwv[e][1] + xa[s][2] * kwv[e][2] + xa[s][3] * kwv[e][3];
    const ushort2 g2 = *(const ushort2*)(gateb + row * 256 + n * 2);
    const float igs = bf2f(g2.x);
    const float f = bf2f(g2.y);
    const float ls = fminf(f, 0.f) - __logf(1.0f + __expf(-fabsf(f)));
    run += ls;
    E[s] = __expf(igs - run);
    en[s] = __expf(-run);
  }
  float qwv[4][4];
#pragma unroll
  for (int e = 0; e < 4; ++e) {
    float4 q4 = *(const float4*)(qw + n * 16 + e * 4);
    qwv[e][0] = q4.x; qwv[e][1] = q4.y; qwv[e][2] = q4.z; qwv[e][3] = q4.w;
  }
  const float4 onwv = *(const float4*)(onw + n * 4);
  const float4 onbv = *(const float4*)(onb + n * 4);
  const float4 skv = *(const float4*)(skp + n * 4);
#pragma unroll
  for (int s = 0; s < 8; ++s) {
    float q0, q1, q2, q3;
    q0 = xa[s][0] * qwv[0][0] + xa[s][1] * qwv[0][1] + xa[s][2] * qwv[0][2] + xa[s][3] * qwv[0][3];
    q1 = xa[s][0] * qwv[1][0] + xa[s][1] * qwv[1][1] + xa[s][2] * qwv[1][2] + xa[s][3] * qwv[1][3];
    q2 = xa[s][0] * qwv[2][0] + xa[s][1] * qwv[2][1] + xa[s][2] * qwv[2][2] + xa[s][3] * qwv[2][3];
    q3 = xa[s][0] * qwv[3][0] + xa[s][1] * qwv[3][1] + xa[s][2] * qwv[3][2] + xa[s][3] * qwv[3][3];
    float csum = 0.f;
    float o0 = 0, o1 = 0, o2 = 0, o3 = 0;
#pragma unroll
    for (int t = 0; t < 8; ++t)
      if (t <= s) {
        const float qkd = (q0 * k[t][0] + q1 * k[t][1] + q2 * k[t][2] + q3 * k[t][3]) * 0.5f;
        const float cc = qkd * E[t];
        csum += cc;
        o0 += cc * v[t][0]; o1 += cc * v[t][1]; o2 += cc * v[t][2]; o3 += cc * v[t][3];
      }
    const float inv = fast_rcp(fmaxf(fabsf(csum), en[s]) + 1e-6f);
    o0 *= inv; o1 *= inv; o2 *= inv; o3 *= inv;
    const float mu = 0.25f * (o0 + o1 + o2 + o3);
    const float d0 = o0 - mu, d1 = o1 - mu, d2 = o2 - mu, d3 = o3 - mu;
    const float var = 0.25f * (d0 * d0 + d1 * d1 + d2 * d2 + d3 * d3);
    const float r = __builtin_amdgcn_rsqf(var + 1e-5f);
    const size_t row = (size_t)(p * 8 + s);
    ushort4 z4 = *(const ushort4*)(xz + row * 1024 + 512 + n * 4);
    ushort4 ge;
    ge.x = f2bf((d0 * r * onwv.x + onbv.x + skv.x * xa[s][0]) * silu_fast(bf2f(z4.x)));
    ge.y = f2bf((d1 * r * onwv.y + onbv.y + skv.y * xa[s][1]) * silu_fast(bf2f(z4.y)));
    ge.z = f2bf((d2 * r * onwv.z + onbv.z + skv.z * xa[s][2]) * silu_fast(bf2f(z4.z)));
    ge.w = f2bf((d3 * r * onwv.w + onbv.w + skv.w * xa[s][3]) * silu_fast(bf2f(z4.w)));
    *(ushort4*)(xab + row * 512 + n * 4) = ge;
  }
}

extern "C" void kernel_launch(void* const* d_in, const int* in_sizes, int n_in,
                              void* d_out, int out_size, void* d_ws, size_t ws_size,
                              hipStream_t stream) {
  const float* x = (const float*)d_in[0];
  const float* fc1w = (const float*)d_in[1];
  const float* fc1b = (const float*)d_in[2];
  const float* fc2w = (const float*)d_in[3];
  const float* fc2b = (const float*)d_in[4];
  const float* ofc1w = (const float*)d_in[5];
  const float* ofc1b = (const float*)d_in[6];
  const float* ofc2w = (const float*)d_in[7];
  const float* ofc2b = (const float*)d_in[8];
  const float* nw = (const float*)d_in[9];
  const float* nb = (const float*)d_in[10];
  const float* upw = (const float*)d_in[11];
  const float* upb = (const float*)d_in[12];
  const float* cw = (const float*)d_in[13];
  const float* cb = (const float*)d_in[14];
  const float* qw = (const float*)d_in[15];
  const float* kw = (const float*)d_in[16];
  const float* igw = (const float*)d_in[17];
  const float* igbias = (const float*)d_in[18];
  const float* fgw = (const float*)d_in[19];
  const float* fgbias = (const float*)d_in[20];
  const float* onw = (const float*)d_in[21];
  const float* onb = (const float*)d_in[22];
  const float* skp = (const float*)d_in[23];
  const float* dww = (const float*)d_in[24];
  const float* dwb = (const float*)d_in[25];
  float* out = (float*)d_out;

  // workspace layout (byte offsets), ~114.3 MB total
  char* ws = (char*)d_ws;
  unsigned short* hbuf = (unsigned short*)ws;               // M*256 bf16  13,107,200
  unsigned short* bufD = (unsigned short*)(ws + 13107200);  // M*256 bf16  13,107,200
  unsigned short* bufA = (unsigned short*)(ws + 26214400);  // M*128 bf16   6,553,600
  unsigned short* xz = (unsigned short*)(ws + 32768000);    // M*1024 bf16 52,428,800
  unsigned short* hmirror = xz;                             // M*256 bf16 (after mlstm layer 1)
  unsigned short* xab = (unsigned short*)(ws + 85196800);   // M*512 bf16  26,214,400
  unsigned short* xflat = xab;                              // alias: dead before conv
  unsigned short* wb = (unsigned short*)(ws + 111411200);   // WB_ELEMS bf16 = 2,916,352
  float* gbias = (float*)(ws + 111411200 + 2916352);        // 512 f32
  // end: 114,329,600

  wprep<<<dim3(5186), 256, 0, stream>>>(fc1w, fc2w, ofc1w, ofc2w, upw, dww, igw, fgw, qw, kw,
                                        igbias, fgbias, wb, gbias);

  dim3 tb(32, 8);
  trans_in<<<dim3(50, 32, 2), tb, 0, stream>>>(x, xflat);
  // in-MLP
  mgemm<1><<<dim3(1, 200), 256, 0, stream>>>(xflat, 128, xflat, 128, 128, wb + OFF_FC1, 128,
                                             fc1b, nullptr, bufA, 128, 128, 0);
  mgemm<0><<<dim3(2, 200), 256, 0, stream>>>(bufA, 128, bufA, 128, 128, wb + OFF_FC2, 128,
                                             fc2b, nullptr, hbuf, 256, 128, 0);

  for (int i = 0; i < 2; ++i) {
    ln_k<<<dim3(6400), 256, 0, stream>>>(hbuf, nw + i * 256, nb + i * 256, bufD, i);
    // up-proj, N=1024 -> xz = [xm | z]
    mgemm<0><<<dim3(8, 200), 256, 0, stream>>>(bufD, 256, bufD, 256, 256,
                                               wb + OFF_UP + (size_t)i * 262144, 256,
                                               upb + i * 1024, nullptr, xz, 1024, 256, 0);
    conv_k<<<dim3(NPOS), 512, 0, stream>>>(xz, cw + i * 2048, cb + i * 512, xab);
    // gates: A = [xa (512) | xm (512)], K=1024, N=256 (interleaved ig/fg) -> bufD
    mgemm<0><<<dim3(2, 200), 256, 0, stream>>>(xab, 512, xz, 1024, 512,
                                               wb + OFF_GW + (size_t)i * 262144, 1024,
                                               gbias + i * 256, nullptr, bufD, 256, 1024, 0);
    mlstm_k<<<dim3(1600), 256, 0, stream>>>(xab, xz, bufD, cw + i * 2048, cb + i * 512,
                                            qw + i * 2048, kw + i * 2048,
                                            onw + i * 512, onb + i * 512, skp + i * 512);
    if (i == 0) {
      mgemm<2><<<dim3(2, 200), 256, 0, stream>>>(xab, 512, xab, 512, 512, wb + OFF_DW, 512,
                                                 dwb, nullptr, hbuf, 256, 512, 0);
    } else {
      mgemm<6><<<dim3(2, 200), 256, 0, stream>>>(xab, 512, xab, 512, 512, wb + OFF_DW + 131072,
                                                 512, dwb + 256, hbuf, hmirror, 256, 512, 1);
    }
  }

  // out-MLP
  mgemm<1><<<dim3(2, 200), 256, 0, stream>>>(hmirror, 256, hmirror, 256, 256, wb + OFF_OFC1, 256,
                                             ofc1b, nullptr, bufD, 256, 256, 0);
  mgemm<0><<<dim3(1, 200), 256, 0, stream>>>(bufD, 256, bufD, 256, 256, wb + OFF_OFC2, 256,
                                             ofc2b, nullptr, bufA, 128, 256, 0);
  trans_out<<<dim3(50, 32, 2), tb, 0, stream>>>(x, bufA, out);
}